// Round 1
// baseline (282.753 us; speedup 1.0000x reference)
//
#include <hip/hip_runtime.h>
#include <math.h>

#define DEV __device__ __forceinline__

struct F3 { float x, y, z; };
DEV F3 f3(float x, float y, float z) { F3 r; r.x = x; r.y = y; r.z = z; return r; }
DEV F3 sub3(F3 a, F3 b) { return f3(a.x - b.x, a.y - b.y, a.z - b.z); }
DEV F3 add3(F3 a, F3 b) { return f3(a.x + b.x, a.y + b.y, a.z + b.z); }
DEV F3 scl3(F3 a, float s) { return f3(a.x * s, a.y * s, a.z * s); }
DEV float dot3(F3 a, F3 b) { return a.x * b.x + a.y * b.y + a.z * b.z; }

#define EXCL_EPS 2.0f
#define PIF 3.14159265358979323846f
#define HPIF 1.57079632679489661923f

DEV float mimg1(float d, float box, float ibox) { return d - box * rintf(d * ibox); }
DEV F3 mimg(F3 d, F3 box, F3 ibox) {
    return f3(mimg1(d.x, box.x, ibox.x), mimg1(d.y, box.y, ibox.y), mimg1(d.z, box.z, ibox.z));
}
DEV float norm3(F3 d) { return sqrtf(dot3(d, d) + 1e-12f); }

DEV float acosc(float c) {
    c = fminf(fmaxf(c, -1.0f + 1e-6f), 1.0f - 1e-6f);
    return acosf(c);
}

// LJ + quadratic smoothing exclusion
DEV float fexcl(float r, float sigma, float rstar, float b, float rc) {
    float res = 0.0f;
    if (r < rc) {
        if (r < rstar) {
            float s = sigma / r;
            float s2 = s * s;
            float s6 = s2 * s2 * s2;
            res = 4.0f * EXCL_EPS * (s6 * s6 - s6);
        } else {
            float d = r - rc;
            res = EXCL_EPS * b * d * d;
        }
    }
    return res;
}

// Morse-like with precomputed shift = (exp(-a*(rc-r0))-1)^2
DEV float f1f(float r, float a, float r0, float shift, float rlow, float rhigh,
              float blow, float rclow, float bhigh, float rchigh) {
    float res = 0.0f;
    if (r > rlow && r < rhigh) {
        float t = __expf(-a * (r - r0)) - 1.0f;
        res = t * t - shift;
    } else if (r > rclow && r <= rlow) {
        float d = r - rclow; res = blow * d * d;
    } else if (r >= rhigh && r < rchigh) {
        float d = r - rchigh; res = bhigh * d * d;
    }
    return res;
}

DEV float f2f(float r, float k, float r0, float rc, float rlow, float rhigh,
              float blow, float rclow, float bhigh, float rchigh) {
    float res = 0.0f;
    if (r > rlow && r < rhigh) {
        float d = r - r0, dc = rc - r0;
        res = 0.5f * k * (d * d - dc * dc);
    } else if (r > rclow && r <= rlow) {
        float d = r - rclow; res = k * blow * d * d;
    } else if (r >= rhigh && r < rchigh) {
        float d = r - rchigh; res = k * bhigh * d * d;
    }
    return res;
}

DEV float f4f(float th, float a, float t0, float ts, float b, float tc) {
    float dt = fabsf(th - t0);
    float res = 0.0f;
    if (dt < ts) res = 1.0f - a * dt * dt;
    else if (dt < tc) { float d = tc - dt; res = b * d * d; }
    return res;
}

DEV float f5f(float x, float a, float xs, float b, float xc) {
    float res = 0.0f;
    if (x > 0.0f) res = 1.0f;
    else if (x > xs) res = 1.0f - a * x * x;
    else if (x > xc) { float d = xc - x; res = b * d * d; }
    return res;
}

DEV void load_particle(const float* __restrict__ pos, const float4* __restrict__ quat, int i,
                       F3& a1, F3& a2, F3& a3, F3& back, F3& stck, F3& base) {
    float4 q = quat[i];
    float n = sqrtf(q.x * q.x + q.y * q.y + q.z * q.z + q.w * q.w + 1e-12f);
    float inv = 1.0f / n;
    float w = q.x * inv, x = q.y * inv, y = q.z * inv, z = q.w * inv;
    a1 = f3(1.0f - 2.0f * (y * y + z * z), 2.0f * (x * y + w * z), 2.0f * (x * z - w * y));
    a2 = f3(2.0f * (x * y - w * z), 1.0f - 2.0f * (x * x + z * z), 2.0f * (y * z + w * x));
    a3 = f3(2.0f * (x * z + w * y), 2.0f * (y * z - w * x), 1.0f - 2.0f * (x * x + y * y));
    F3 p = f3(pos[3 * i], pos[3 * i + 1], pos[3 * i + 2]);
    back = add3(p, scl3(a1, -0.4f));
    stck = add3(p, scl3(a1, 0.34f));
    base = add3(p, scl3(a1, 0.4f));
}

// block = 256 threads = 4 waves; double reduce, atomic to one of 64 slots
DEV void block_reduce_atomic(float e, double* __restrict__ slots) {
    double v = (double)e;
#pragma unroll
    for (int off = 32; off > 0; off >>= 1) v += __shfl_down(v, off, 64);
    __shared__ double red[4];
    int lane = threadIdx.x & 63;
    int wv = threadIdx.x >> 6;
    if (lane == 0) red[wv] = v;
    __syncthreads();
    if (threadIdx.x == 0) {
        double s = red[0] + red[1] + red[2] + red[3];
        atomicAdd(slots + (blockIdx.x & 63), s);
    }
}

__global__ void __launch_bounds__(256)
bonded_kernel(const float* __restrict__ pos, const float4* __restrict__ quat,
              const float* __restrict__ seps, const float* __restrict__ boxp,
              const int2* __restrict__ pairs, int n, double* __restrict__ slots) {
    int t = blockIdx.x * blockDim.x + threadIdx.x;
    float e = 0.0f;
    if (t < n) {
        float bx = boxp[0], by = boxp[1], bz = boxp[2];
        F3 box = f3(bx, by, bz);
        F3 ibox = f3(1.0f / bx, 1.0f / by, 1.0f / bz);
        int2 p = pairs[t];
        int i = p.x, j = p.y;
        F3 a1i, a2i, a3i, backi, stcki, basei;
        F3 a1j, a2j, a3j, backj, stckj, basej;
        load_particle(pos, quat, i, a1i, a2i, a3i, backi, stcki, basei);
        load_particle(pos, quat, j, a1j, a2j, a3j, backj, stckj, basej);

        // FENE on backbone sites
        F3 dbb = mimg(sub3(backj, backi), box, ibox);
        float rbb = norm3(dbb);
        float u = (rbb - 0.7525f) * 4.0f;  // /FENE_DELTA(0.25)
        float arg = u * u;
        arg = fminf(fmaxf(arg, 0.0f), 1.0f - 1e-6f);
        e += -0.5f * 2.0f * log1pf(-arg);  // FENE_EPS=2

        // bonded exclusions
        e += fexcl(norm3(mimg(sub3(basej, basei), box, ibox)), 0.33f, 0.32f, 4119.70450017f, 0.335388426126f);
        e += fexcl(norm3(mimg(sub3(basej, backi), box, ibox)), 0.515f, 0.5f, 2047.42812499f, 0.52329943261f);
        e += fexcl(norm3(mimg(sub3(backj, basei), box, ibox)), 0.515f, 0.5f, 2047.42812499f, 0.52329943261f);

        // stacking
        F3 ds = mimg(sub3(stckj, stcki), box, ibox);
        float rs = norm3(ds);
        F3 rhat = scl3(ds, 1.0f / rs);
        float t4 = acosc(dot3(a3i, a3j));
        float t5 = acosc(dot3(a3j, rhat));
        float t6 = acosc(-dot3(a3i, rhat));
        F3 rbhat = scl3(dbb, 1.0f / rbb);
        float cphi1 = dot3(a2i, rbhat);
        float cphi2 = dot3(a2j, rbhat);
        float st = seps[t]
                 * f1f(rs, 6.0f, 0.4f, 0.90290461f, 0.32f, 0.75f, -0.68f, 0.26f, -12.6f, 0.8f)
                 * f4f(t4, 1.3f, 0.0f, 0.8f, 6.4f, 0.961538f)
                 * f4f(t5, 0.9f, 0.0f, 0.95f, 3.9f, 1.16959f)
                 * f4f(t6, 0.9f, 0.0f, 0.95f, 3.9f, 1.16959f)
                 * f5f(cphi1, 2.0f, -0.65f, 10.9032f, -0.769231f)
                 * f5f(cphi2, 2.0f, -0.65f, 10.9032f, -0.769231f);
        e += st;
    }
    block_reduce_atomic(e, slots);
}

__global__ void __launch_bounds__(256)
nonbonded_kernel(const float* __restrict__ pos, const float4* __restrict__ quat,
                 const float* __restrict__ hbe, const float* __restrict__ boxp,
                 const int2* __restrict__ pairs, const int* __restrict__ btypes,
                 int n, double* __restrict__ slots) {
    int t = blockIdx.x * blockDim.x + threadIdx.x;
    float e = 0.0f;
    if (t < n) {
        float bx = boxp[0], by = boxp[1], bz = boxp[2];
        F3 box = f3(bx, by, bz);
        F3 ibox = f3(1.0f / bx, 1.0f / by, 1.0f / bz);
        int2 p = pairs[t];
        int i = p.x, j = p.y;
        F3 a1i, a2i, a3i, backi, stcki, basei;
        F3 a1j, a2j, a3j, backj, stckj, basej;
        load_particle(pos, quat, i, a1i, a2i, a3i, backi, stcki, basei);
        load_particle(pos, quat, j, a1j, a2j, a3j, backj, stckj, basej);

        // nonbonded exclusions
        e += fexcl(norm3(mimg(sub3(backj, backi), box, ibox)), 0.7f, 0.675f, 892.016223343f, 0.711879214356f);
        F3 dbase = mimg(sub3(basej, basei), box, ibox);
        float rb = norm3(dbase);
        e += fexcl(rb, 0.33f, 0.32f, 4119.70450017f, 0.335388426126f);
        e += fexcl(norm3(mimg(sub3(basej, backi), box, ibox)), 0.515f, 0.5f, 2047.42812499f, 0.52329943261f);
        e += fexcl(norm3(mimg(sub3(backj, basei), box, ibox)), 0.515f, 0.5f, 2047.42812499f, 0.52329943261f);

        // hydrogen bonding angles
        F3 rhat = scl3(dbase, 1.0f / rb);
        float t1  = acosc(-dot3(a1i, a1j));
        float t2  = acosc(-dot3(a1j, rhat));
        float t3  = acosc(dot3(a1i, rhat));
        float t4h = acosc(dot3(a3i, a3j));
        float t7  = acosc(-dot3(a3j, rhat));
        float t8  = acosc(dot3(a3i, rhat));

        int bti = btypes[i], btj = btypes[j];
        float eps = hbe[bti * 4 + btj];
        float f4t7 = f4f(t7, 4.0f, HPIF, 0.45f, 17.0526f, 0.555556f);
        float e_hb = eps
                   * f1f(rb, 8.0f, 0.4f, 0.88207774f, 0.34f, 0.7f, -126.2f, 0.276f, -7.87f, 0.783f)
                   * f4f(t1, 1.5f, 0.0f, 0.7f, 4.16038f, 0.952381f)
                   * f4f(t2, 1.5f, 0.0f, 0.7f, 4.16038f, 0.952381f)
                   * f4f(t3, 1.5f, 0.0f, 0.7f, 4.16038f, 0.952381f)
                   * f4f(t4h, 0.46f, PIF, 0.7f, 1.14813f, 3.0f)
                   * f4t7
                   * f4f(t8, 4.0f, HPIF, 0.45f, 17.0526f, 0.555556f);
        e += e_hb;

        // cross-stacking
        float e_cr = f2f(rb, 47.5f, 0.575f, 0.675f, 0.495f, 0.655f, -0.888f, 0.45f, -0.888f, 0.68f)
                   * f4f(t1, 2.25f, 0.791592653589793f, 0.58f, 10.9032f, 0.766284f)
                   * f4f(t4h, 1.5f, 0.0f, 0.7f, 4.16038f, 0.952381f)
                   * (f4t7 + f4f(PIF - t7, 4.0f, HPIF, 0.45f, 17.0526f, 0.555556f));
        e += e_cr;

        // coaxial stacking
        F3 dc = mimg(sub3(stckj, stcki), box, ibox);
        float rcx = norm3(dc);
        F3 rchat = scl3(dc, 1.0f / rcx);
        float ct5 = acosc(dot3(a3j, rchat));
        float cphi3 = dot3(a2i, a2j);
        float e_cx = f2f(rcx, 46.0f, 0.4f, 0.6f, 0.22f, 0.58f, -0.7f, 0.2f, -0.7f, 0.62f)
                   * f4f(t1, 2.0f, 2.592f, 0.65f, 10.9032f, 0.766284f)
                   * f4f(t4h, 1.3f, 0.0f, 0.8f, 6.4f, 0.961538f)
                   * f4f(ct5, 0.9f, 0.0f, 0.95f, 3.9f, 1.16959f)
                   * f5f(cphi3, 2.0f, -0.65f, 10.9032f, -0.769231f);
        e += e_cx;
    }
    block_reduce_atomic(e, slots);
}

__global__ void finalize_kernel(const double* __restrict__ slots, float* __restrict__ out) {
    double v = slots[threadIdx.x];
#pragma unroll
    for (int off = 32; off > 0; off >>= 1) v += __shfl_down(v, off, 64);
    if (threadIdx.x == 0) out[0] = (float)v;
}

extern "C" void kernel_launch(void* const* d_in, const int* in_sizes, int n_in,
                              void* d_out, int out_size, void* d_ws, size_t ws_size,
                              hipStream_t stream) {
    const float*  pos  = (const float*)d_in[0];
    const float4* quat = (const float4*)d_in[1];
    const float*  seps = (const float*)d_in[2];
    const float*  hbe  = (const float*)d_in[3];
    const float*  boxp = (const float*)d_in[4];
    const int2*   bp   = (const int2*)d_in[5];
    const int2*   nbp  = (const int2*)d_in[6];
    const int*    bt   = (const int*)d_in[7];

    double* slots = (double*)d_ws;  // 64 accumulation slots
    hipMemsetAsync(slots, 0, 64 * sizeof(double), stream);

    int n_b  = in_sizes[5] / 2;
    int n_nb = in_sizes[6] / 2;

    bonded_kernel<<<(n_b + 255) / 256, 256, 0, stream>>>(pos, quat, seps, boxp, bp, n_b, slots);
    nonbonded_kernel<<<(n_nb + 255) / 256, 256, 0, stream>>>(pos, quat, hbe, boxp, nbp, bt, n_nb, slots);
    finalize_kernel<<<1, 64, 0, stream>>>(slots, (float*)d_out);
}